// Round 12
// baseline (209.616 us; speedup 1.0000x reference)
//
#include <hip/hip_runtime.h>
#include <hip/hip_bf16.h>
#include <math.h>

#define B_ 8
#define N_ 1024
#define E_ 1024
#define H_ 16
#define D_ 64

typedef __attribute__((ext_vector_type(8))) short short8;
typedef __attribute__((ext_vector_type(4))) float f32x4;

static __device__ __forceinline__ unsigned short f2bf(float f) {
    __hip_bfloat16 h = __float2bfloat16(f);
    return __builtin_bit_cast(unsigned short, h);
}
static __device__ __forceinline__ unsigned int cvtpk_bf16(float a, float b) {
    unsigned int r;
    asm("v_cvt_pk_bf16_f32 %0, %1, %2" : "=v"(r) : "v"(a), "v"(b));
    return r;  // low16 = bf16(a), high16 = bf16(b)
}
static __device__ __forceinline__ float fast_rcp(float x) {
    float r;
    asm("v_rcp_f32 %0, %1" : "=v"(r) : "v"(x));
    return r;  // ~1 ulp
}
static __device__ __forceinline__ void gld_lds16(const void* g, void* l) {
    __builtin_amdgcn_global_load_lds(
        (const __attribute__((address_space(1))) unsigned int*)g,
        (__attribute__((address_space(3))) unsigned int*)l, 16, 0, 0);
}

// ---------------------------------------------------------------------------
// Fused fp32->bf16 conversions + temb layer 1, flat grid (verified round 11)
// ---------------------------------------------------------------------------
__global__ __launch_bounds__(256) void cvt_fused(
    const float* __restrict__ ej, const float* __restrict__ w0,
    const float* __restrict__ w1, const float* __restrict__ w2,
    const float* __restrict__ w3,
    unsigned short* __restrict__ ejd, unsigned short* __restrict__ d0,
    unsigned short* __restrict__ d1, unsigned short* __restrict__ d2,
    unsigned short* __restrict__ d3,
    const float* __restrict__ t, const float* __restrict__ tW1,
    const float* __restrict__ tb1, float* __restrict__ h1T)
{
    const int gid = blockIdx.x;
    const int tid = threadIdx.x;
    if (gid < 12288) {
        const float* s; unsigned short* d; int i;
        if (gid < 8192) {
            s = ej; d = ejd; i = (gid * 256 + tid) * 4;
        } else {
            int w = (gid - 8192) >> 10;
            s = w == 0 ? w0 : (w == 1 ? w1 : (w == 2 ? w2 : w3));
            d = w == 0 ? d0 : (w == 1 ? d1 : (w == 2 ? d2 : d3));
            i = (((gid - 8192) & 1023) * 256 + tid) * 4;
        }
        float4 v = *(const float4*)(s + i);
        *(ushort4*)(d + i) = make_ushort4(f2bf(v.x), f2bf(v.y), f2bf(v.z), f2bf(v.w));
        return;
    }
    const int wv = tid >> 6, lane = tid & 63;
    const int j = (gid - 12288) * 4 + wv;  // 0..511
    float tv[8];
#pragma unroll
    for (int b = 0; b < 8; ++b) tv[b] = t[b];
    const float* w = tW1 + j * 1024;
    float acc[8];
#pragma unroll
    for (int b = 0; b < 8; ++b) acc[b] = 0.f;
    const float kLog = 9.210340371976184f;
    for (int e = lane; e < 1024; e += 64) {
        float we = w[e];
        int ef = e & 511;
        float freq = __expf(-kLog * (float)ef * (1.0f / 512.0f));
        if (e < 512) {
#pragma unroll
            for (int b = 0; b < 8; ++b) acc[b] = fmaf(we, __cosf(tv[b] * freq), acc[b]);
        } else {
#pragma unroll
            for (int b = 0; b < 8; ++b) acc[b] = fmaf(we, __sinf(tv[b] * freq), acc[b]);
        }
    }
#pragma unroll
    for (int off = 32; off > 0; off >>= 1)
#pragma unroll
        for (int b = 0; b < 8; ++b) acc[b] += __shfl_xor(acc[b], off, 64);
    if (lane == 0) {
        float bias = tb1[j];
#pragma unroll
        for (int b = 0; b < 8; ++b) h1T[j * 8 + b] = fmaxf(acc[b] + bias, 0.f);
    }
}

// ---------------------------------------------------------------------------
// temb layer 2 (verified)
// ---------------------------------------------------------------------------
__global__ __launch_bounds__(256) void temb2_kernel(
    const float* __restrict__ h1T, const float* __restrict__ tW2,
    const float* __restrict__ tb2, float* __restrict__ temb)
{
    const int wv = threadIdx.x >> 6, lane = threadIdx.x & 63;
    const int e2 = blockIdx.x * 4 + wv;
    const float* w = tW2 + e2 * 512;
    float acc[8];
#pragma unroll
    for (int b = 0; b < 8; ++b) acc[b] = 0.f;
    for (int j = lane; j < 512; j += 64) {
        float wv_ = w[j];
        const float* hp = h1T + j * 8;
#pragma unroll
        for (int b = 0; b < 8; ++b) acc[b] = fmaf(hp[b], wv_, acc[b]);
    }
#pragma unroll
    for (int off = 32; off > 0; off >>= 1)
#pragma unroll
        for (int b = 0; b < 8; ++b) acc[b] += __shfl_xor(acc[b], off, 64);
    if (lane == 0) {
        float bias = tb2[e2];
#pragma unroll
        for (int b = 0; b < 8; ++b) temb[b * 1024 + e2] = acc[b] + bias;
    }
}

// ---------------------------------------------------------------------------
// 2-phase double-buffered bf16 MFMA K-loop, 128x128 tile (verified: 757 TF)
// ---------------------------------------------------------------------------
static __device__ __forceinline__ void gemm_loop(
    const unsigned short* __restrict__ A, const unsigned short* __restrict__ Bm,
    int m0, int n0, int K,
    unsigned short* As0, unsigned short* As1,
    unsigned short* Bs0, unsigned short* Bs1,
    f32x4 acc[4][4])
{
    const int tid = threadIdx.x;
    const int wave = tid >> 6, lane = tid & 63;
    const int wm = wave >> 1, wn = wave & 1;
    const int sr = lane >> 2, sc = (lane & 3) * 8;
    const unsigned short* Ag0 = A + (size_t)(m0 + wave * 16 + sr) * K + sc;
    const unsigned short* Ag1 = A + (size_t)(m0 + 64 + wave * 16 + sr) * K + sc;
    const unsigned short* Bg0 = Bm + (size_t)(n0 + wave * 16 + sr) * K + sc;
    const unsigned short* Bg1 = Bm + (size_t)(n0 + 64 + wave * 16 + sr) * K + sc;

    const f32x4 zero = {0.f, 0.f, 0.f, 0.f};
#pragma unroll
    for (int i = 0; i < 4; ++i)
#pragma unroll
        for (int j = 0; j < 4; ++j) acc[i][j] = zero;

    gld_lds16(Ag0, As0 + wave * 512);
    gld_lds16(Ag1, As0 + (wave + 4) * 512);
    gld_lds16(Bg0, Bs0 + wave * 512);
    gld_lds16(Bg1, Bs0 + (wave + 4) * 512);
    __syncthreads();

    const int fr = lane & 15, fq = (lane >> 4) * 8;
    int cur = 0;
    for (int k0 = 0; k0 < K; k0 += 32) {
        const unsigned short* sA = cur ? As1 : As0;
        const unsigned short* sB = cur ? Bs1 : Bs0;
        unsigned short* dA = cur ? As0 : As1;
        unsigned short* dB = cur ? Bs0 : Bs1;
        if (k0 + 32 < K) {
            gld_lds16(Ag0 + k0 + 32, dA + wave * 512);
            gld_lds16(Ag1 + k0 + 32, dA + (wave + 4) * 512);
            gld_lds16(Bg0 + k0 + 32, dB + wave * 512);
            gld_lds16(Bg1 + k0 + 32, dB + (wave + 4) * 512);
        }
        short8 af[4], bf[4];
#pragma unroll
        for (int i = 0; i < 4; ++i) {
            af[i] = *(const short8*)&sA[(wm * 64 + i * 16 + fr) * 32 + fq];
            bf[i] = *(const short8*)&sB[(wn * 64 + i * 16 + fr) * 32 + fq];
        }
#pragma unroll
        for (int i = 0; i < 4; ++i)
#pragma unroll
            for (int j = 0; j < 4; ++j)
                acc[i][j] = __builtin_amdgcn_mfma_f32_16x16x32_bf16(
                    af[i], bf[j], acc[i][j], 0, 0, 0);
        __syncthreads();
        cur ^= 1;
    }
}

// ---------------------------------------------------------------------------
// 2-phase double-buffered bf16 MFMA K-loop, 64x128 tile (verified)
// ---------------------------------------------------------------------------
static __device__ __forceinline__ void gemm_loop64(
    const unsigned short* __restrict__ A, const unsigned short* __restrict__ Bm,
    int m0, int n0, int K,
    unsigned short* As0, unsigned short* As1,
    unsigned short* Bs0, unsigned short* Bs1,
    f32x4 acc[2][4])
{
    const int tid = threadIdx.x;
    const int wave = tid >> 6, lane = tid & 63;
    const int wm = wave >> 1, wn = wave & 1;
    const int sr = lane >> 2, sc = (lane & 3) * 8;
    const unsigned short* Ag0 = A + (size_t)(m0 + wave * 16 + sr) * K + sc;
    const unsigned short* Bg0 = Bm + (size_t)(n0 + wave * 16 + sr) * K + sc;
    const unsigned short* Bg1 = Bm + (size_t)(n0 + 64 + wave * 16 + sr) * K + sc;

    const f32x4 zero = {0.f, 0.f, 0.f, 0.f};
#pragma unroll
    for (int i = 0; i < 2; ++i)
#pragma unroll
        for (int j = 0; j < 4; ++j) acc[i][j] = zero;

    gld_lds16(Ag0, As0 + wave * 512);
    gld_lds16(Bg0, Bs0 + wave * 512);
    gld_lds16(Bg1, Bs0 + (wave + 4) * 512);
    __syncthreads();

    const int fr = lane & 15, fq = (lane >> 4) * 8;
    int cur = 0;
    for (int k0 = 0; k0 < K; k0 += 32) {
        const unsigned short* sA = cur ? As1 : As0;
        const unsigned short* sB = cur ? Bs1 : Bs0;
        unsigned short* dA = cur ? As0 : As1;
        unsigned short* dB = cur ? Bs0 : Bs1;
        if (k0 + 32 < K) {
            gld_lds16(Ag0 + k0 + 32, dA + wave * 512);
            gld_lds16(Bg0 + k0 + 32, dB + wave * 512);
            gld_lds16(Bg1 + k0 + 32, dB + (wave + 4) * 512);
        }
        short8 af[2], bf[4];
#pragma unroll
        for (int i = 0; i < 2; ++i)
            af[i] = *(const short8*)&sA[(wm * 32 + i * 16 + fr) * 32 + fq];
#pragma unroll
        for (int j = 0; j < 4; ++j)
            bf[j] = *(const short8*)&sB[(wn * 64 + j * 16 + fr) * 32 + fq];
#pragma unroll
        for (int i = 0; i < 2; ++i)
#pragma unroll
            for (int j = 0; j < 4; ++j)
                acc[i][j] = __builtin_amdgcn_mfma_f32_16x16x32_bf16(
                    af[i], bf[j], acc[i][j], 0, 0, 0);
        __syncthreads();
        cur ^= 1;
    }
}

// fused Q/K/V projection, 128x128 tile, grid(1536) XCD-swizzled
__global__ __launch_bounds__(256) void qkv_gemm(
    const unsigned short* __restrict__ A,
    const unsigned short* __restrict__ W0, const unsigned short* __restrict__ W1,
    const unsigned short* __restrict__ W2,
    unsigned short* __restrict__ C0, unsigned short* __restrict__ C1,
    unsigned short* __restrict__ C2)
{
    __shared__ unsigned short As0[128 * 32], As1[128 * 32];
    __shared__ unsigned short Bs0[128 * 32], Bs1[128 * 32];
    const int orig = blockIdx.x;
    const int sw = (orig & 7) * 192 + (orig >> 3);
    const int z = sw / 512, r = sw & 511;
    const int m0 = (r >> 3) * 128, n0 = (r & 7) * 128;
    const unsigned short* W = z == 0 ? W0 : (z == 1 ? W1 : W2);
    unsigned short* C = z == 0 ? C0 : (z == 1 ? C1 : C2);

    f32x4 acc[4][4];
    gemm_loop(A, W, m0, n0, 1024, As0, As1, Bs0, Bs1, acc);

    const int lane = threadIdx.x & 63, wave = threadIdx.x >> 6;
    const int wm = wave >> 1, wn = wave & 1;
    const int fr = lane & 15, fq4 = (lane >> 4) * 4;
#pragma unroll
    for (int i = 0; i < 4; ++i) {
        int row = m0 + wm * 64 + i * 16 + fq4;
#pragma unroll
        for (int j = 0; j < 4; ++j) {
            int col = n0 + wn * 64 + j * 16 + fr;
#pragma unroll
            for (int rr = 0; rr < 4; ++rr)
                C[(size_t)(row + rr) * 1024 + col] = f2bf(acc[i][j][rr]);
        }
    }
}

// out-projection (+bias+temb), 64x128 tile, grid(1024) XCD-swizzled
__global__ __launch_bounds__(256) void outproj_gemm(
    const unsigned short* __restrict__ A, const unsigned short* __restrict__ Bm,
    unsigned short* __restrict__ C,
    const float* __restrict__ bias, const float* __restrict__ temb)
{
    __shared__ unsigned short As0[64 * 32], As1[64 * 32];
    __shared__ unsigned short Bs0[128 * 32], Bs1[128 * 32];
    const int orig = blockIdx.x;
    const int sw = (orig & 7) * 128 + (orig >> 3);
    const int mt = sw >> 3, n0 = (sw & 7) * 128;
    const int m0 = mt * 64;

    f32x4 acc[2][4];
    gemm_loop64(A, Bm, m0, n0, 1024, As0, As1, Bs0, Bs1, acc);

    const int lane = threadIdx.x & 63, wave = threadIdx.x >> 6;
    const int wm = wave >> 1, wn = wave & 1;
    const int fr = lane & 15, fq4 = (lane >> 4) * 4;
    const int bb = m0 >> 10;
#pragma unroll
    for (int i = 0; i < 2; ++i) {
        int row = m0 + wm * 32 + i * 16 + fq4;
#pragma unroll
        for (int j = 0; j < 4; ++j) {
            int col = n0 + wn * 64 + j * 16 + fr;
            float epi = bias[col] + temb[bb * 1024 + col];
#pragma unroll
            for (int rr = 0; rr < 4; ++rr)
                C[(size_t)(row + rr) * 1024 + col] = f2bf(acc[i][j][rr] + epi);
        }
    }
}

// ---------------------------------------------------------------------------
// MFMA flash attention, qt=4, K/V DOUBLE-BUFFERED with ONE barrier per tile:
// writes of tile t+1 (into buf^1) overlap compute of tile t (buf); prefetch
// loads for t+2 issued first (T14).  Two named register sets (no runtime
// indexing).  Swapped-operand, P in registers (kv permutation), bounded-score
// softmax, l via ones-row on matrix pipe.  grid 512 (2 blocks/CU).
// ---------------------------------------------------------------------------
__global__ __launch_bounds__(256, 2) void attn_mfma(
    const unsigned short* __restrict__ Q, const unsigned short* __restrict__ K,
    const unsigned short* __restrict__ V, unsigned short* __restrict__ O)
{
    __shared__ __align__(16) unsigned short Ks[2][64 * 72];
    __shared__ __align__(16) unsigned short Vts[2][64 * 72];
    __shared__ __align__(16) unsigned short Vone[16 * 72];  // row 0 = ones
    const int tid = threadIdx.x;
    const int wq = tid >> 6, lane = tid & 63;
    const int lo = lane & 15, hi = lane >> 4;
    const int id = blockIdx.x;                 // 512 blocks
    const int sw = (id & 7) * 64 + (id >> 3);  // bijective XCD swizzle
    const int q0 = (sw & 3) * 256;
    const int h = (sw >> 2) & 15, b = sw >> 6;
    const size_t base = ((size_t)b * N_) * 1024 + h * 64;

    for (int i = tid; i < 16 * 64; i += 256) {
        int rr = i >> 6, cc = i & 63;
        Vone[rr * 72 + cc] = (rr == 0) ? (unsigned short)0x3F80 : (unsigned short)0;
    }

    // Q B-frags (row=q=lo, k=d), 4 q-tiles per wave, read once
    short8 aq[4][2];
#pragma unroll
    for (int qt = 0; qt < 4; ++qt)
#pragma unroll
        for (int ks = 0; ks < 2; ++ks)
            aq[qt][ks] = *(const short8*)(Q + base +
                (size_t)(q0 + wq * 64 + qt * 16 + lo) * 1024 + hi * 8 + ks * 32);

    f32x4 o_[4][5];   // [qt][db]; db=4 is the l-row
    const f32x4 zero = {0.f, 0.f, 0.f, 0.f};
#pragma unroll
    for (int qt = 0; qt < 4; ++qt)
#pragma unroll
        for (int db = 0; db < 5; ++db) o_[qt][db] = zero;

    const int kr = tid >> 2, ku = (tid & 3) * 16;
    const unsigned short* Kg = K + base + (size_t)kr * 1024 + ku;
    const int vkv = (tid & 31) * 2, vd = (tid >> 5) * 8;
    const int scol = (vkv & 0x23) | ((vkv & 0x0C) << 1) | ((vkv & 0x10) >> 2);
    const unsigned short* Vg = V + base + (size_t)vkv * 1024 + vd;

    const float cexp = 0.1803368801111204f;  // log2(e)/8

    auto write_tile = [&](unsigned short* KB, unsigned short* VB,
                          short8 k0, short8 k1, short8 va, short8 vb_) {
        *(short8*)&KB[kr * 72 + ku] = k0;
        *(short8*)&KB[kr * 72 + ku + 8] = k1;
#pragma unroll
        for (int i = 0; i < 8; ++i) {
            unsigned int pv = (unsigned int)(unsigned short)va[i] |
                              ((unsigned int)(unsigned short)vb_[i] << 16);
            *(unsigned int*)&VB[(vd + i) * 72 + scol] = pv;
        }
    };

    short8 vb4[2];
    auto compute_tile = [&](const unsigned short* KB, const unsigned short* VB) {
        short8 kb[4][2], vb[4][2];
#pragma unroll
        for (int jk = 0; jk < 4; ++jk)
#pragma unroll
            for (int ks = 0; ks < 2; ++ks)
                kb[jk][ks] = *(const short8*)&KB[(16 * jk + lo) * 72 + hi * 8 + ks * 32];
#pragma unroll
        for (int db = 0; db < 4; ++db)
#pragma unroll
            for (int k2 = 0; k2 < 2; ++k2)
                vb[db][k2] = *(const short8*)&VB[(16 * db + lo) * 72 + hi * 8 + k2 * 32];

#pragma unroll
        for (int qt = 0; qt < 4; ++qt) {
            f32x4 s[4];
            __builtin_amdgcn_s_setprio(1);
#pragma unroll
            for (int jk = 0; jk < 4; ++jk) {
                s[jk] = __builtin_amdgcn_mfma_f32_16x16x32_bf16(
                    kb[jk][0], aq[qt][0], zero, 0, 0, 0);
                s[jk] = __builtin_amdgcn_mfma_f32_16x16x32_bf16(
                    kb[jk][1], aq[qt][1], s[jk], 0, 0, 0);
            }
            __builtin_amdgcn_s_setprio(0);
#pragma unroll
            for (int jk = 0; jk < 4; ++jk)
#pragma unroll
                for (int rr = 0; rr < 4; ++rr)
                    s[jk][rr] = exp2f(s[jk][rr] * cexp);
            unsigned int pw[8];
#pragma unroll
            for (int jk = 0; jk < 4; ++jk) {
                pw[2 * jk] = cvtpk_bf16(s[jk][0], s[jk][1]);
                pw[2 * jk + 1] = cvtpk_bf16(s[jk][2], s[jk][3]);
            }
            uint4 pa0 = make_uint4(pw[0], pw[1], pw[2], pw[3]);
            uint4 pa1 = make_uint4(pw[4], pw[5], pw[6], pw[7]);
            short8 pA = __builtin_bit_cast(short8, pa0);
            short8 pB = __builtin_bit_cast(short8, pa1);

            __builtin_amdgcn_s_setprio(1);
#pragma unroll
            for (int db = 0; db < 4; ++db) {
                o_[qt][db] = __builtin_amdgcn_mfma_f32_16x16x32_bf16(
                    vb[db][0], pA, o_[qt][db], 0, 0, 0);
                o_[qt][db] = __builtin_amdgcn_mfma_f32_16x16x32_bf16(
                    vb[db][1], pB, o_[qt][db], 0, 0, 0);
            }
            o_[qt][4] = __builtin_amdgcn_mfma_f32_16x16x32_bf16(
                vb4[0], pA, o_[qt][4], 0, 0, 0);
            o_[qt][4] = __builtin_amdgcn_mfma_f32_16x16x32_bf16(
                vb4[1], pB, o_[qt][4], 0, 0, 0);
            __builtin_amdgcn_s_setprio(0);
        }
    };

    // ---- prologue: tile 0 -> buf0 (set A); tile 1 -> regs (set B) ----
    short8 kA0 = *(const short8*)(Kg);
    short8 kA1 = *(const short8*)(Kg + 8);
    short8 vAa = *(const short8*)(Vg);
    short8 vAb = *(const short8*)(Vg + 1024);
    write_tile(Ks[0], Vts[0], kA0, kA1, vAa, vAb);
    short8 kB0 = *(const short8*)(Kg + (size_t)64 * 1024);
    short8 kB1 = *(const short8*)(Kg + (size_t)64 * 1024 + 8);
    short8 vBa = *(const short8*)(Vg + (size_t)64 * 1024);
    short8 vBb = *(const short8*)(Vg + (size_t)64 * 1024 + 1024);
    __syncthreads();   // publish Vone + buf0
#pragma unroll
    for (int k2 = 0; k2 < 2; ++k2)
        vb4[k2] = *(const short8*)&Vone[lo * 72 + hi * 8 + k2 * 32];

    // ---- main loop: 2 tiles per iteration, 1 barrier per tile ----
    for (int kt = 0; kt < N_; kt += 128) {
        // even tile kt: compute buf0; write tile kt+64 (set B) -> buf1;
        // load tile kt+128 -> set A
        if (kt + 128 < N_) {
            kA0 = *(const short8*)(Kg + (size_t)(kt + 128) * 1024);
            kA1 = *(const short8*)(Kg + (size_t)(kt + 128) * 1024 + 8);
            vAa = *(const short8*)(Vg + (size_t)(kt + 128) * 1024);
            vAb = *(const short8*)(Vg + (size_t)(kt + 128) * 1024 + 1024);
        }
        write_tile(Ks[1], Vts[1], kB0, kB1, vBa, vBb);
        compute_tile(Ks[0], Vts[0]);
        __syncthreads();   // publish buf1; buf0 reads done -> writable

        // odd tile kt+64: compute buf1; write tile kt+128 (set A) -> buf0;
        // load tile kt+192 -> set B
        if (kt + 192 < N_) {
            kB0 = *(const short8*)(Kg + (size_t)(kt + 192) * 1024);
            kB1 = *(const short8*)(Kg + (size_t)(kt + 192) * 1024 + 8);
            vBa = *(const short8*)(Vg + (size_t)(kt + 192) * 1024);
            vBb = *(const short8*)(Vg + (size_t)(kt + 192) * 1024 + 1024);
        }
        if (kt + 128 < N_)
            write_tile(Ks[0], Vts[0], kA0, kA1, vAa, vAb);
        compute_tile(Ks[1], Vts[1]);
        if (kt + 128 < N_)
            __syncthreads();   // publish buf0; buf1 writable next iter
    }

    // ---- epilogue: l for q=lo sits in lane (hi=0,lo), o_[qt][4][0] ----
#pragma unroll
    for (int qt = 0; qt < 4; ++qt) {
        float lsum = __shfl(o_[qt][4][0], lo, 64);
        float inv = fast_rcp(lsum);
        const size_t rb = base + (size_t)(q0 + wq * 64 + qt * 16 + lo) * 1024;
#pragma unroll
        for (int db = 0; db < 4; ++db) {
            *(ushort4*)(O + rb + 16 * db + 4 * hi) = make_ushort4(
                f2bf(o_[qt][db][0] * inv), f2bf(o_[qt][db][1] * inv),
                f2bf(o_[qt][db][2] * inv), f2bf(o_[qt][db][3] * inv));
        }
    }
}

// ---------------------------------------------------------------------------
// Score GEMM + tanh clip + 1x1 conv + 2-way softmax.  64x128 tile,
// grid(1024) XCD-swizzled.  Fast transcendentals + v_rcp.
// ---------------------------------------------------------------------------
__global__ __launch_bounds__(256) void score_bf16(
    const unsigned short* __restrict__ MH, const unsigned short* __restrict__ EJ,
    const float* __restrict__ xt, const float* __restrict__ convw,
    const float* __restrict__ convb, float* __restrict__ out)
{
    __shared__ unsigned short As0[64 * 32], As1[64 * 32];
    __shared__ unsigned short Bs0[128 * 32], Bs1[128 * 32];
    const int orig = blockIdx.x;
    const int sw = (orig & 7) * 128 + (orig >> 3);
    const int bz = sw >> 7;
    const int m0 = ((sw >> 3) & 15) * 64, n0 = (sw & 7) * 128;
    const unsigned short* A = MH + (size_t)bz * N_ * E_;
    const unsigned short* Bm = EJ + (size_t)bz * N_ * E_;

    f32x4 acc[2][4];
    gemm_loop64(A, Bm, m0, n0, 1024, As0, As1, Bs0, Bs1, acc);

    const int lane = threadIdx.x & 63, wave = threadIdx.x >> 6;
    const int wm = wave >> 1, wn = wave & 1;
    const int fr = lane & 15, fq4 = (lane >> 4) * 4;
    const float w00 = convw[0], w01 = convw[1], w10 = convw[2], w11 = convw[3];
    const float cb0 = convb[0], cb1 = convb[1];
    const float L2E = 1.4426950408889634f;
    const float kT = -2.f * L2E * 0.03125f;
#pragma unroll
    for (int i = 0; i < 2; ++i) {
#pragma unroll
        for (int rr = 0; rr < 4; ++rr) {
            int row = m0 + wm * 32 + i * 16 + fq4 + rr;
            const float* xrow = xt + ((size_t)bz * N_ + row) * N_;
            float2* orow = (float2*)(out + (((size_t)bz * N_ + row) * N_) * 2);
#pragma unroll
            for (int j = 0; j < 4; ++j) {
                int col = n0 + wn * 64 + j * 16 + fr;
                float e = exp2f(acc[i][j][rr] * kT);
                float sc_ = fmaf(20.f, fast_rcp(1.f + e), -10.f);  // 10*tanh
                float x = xrow[col];
                float c0 = fmaf(w00, sc_, fmaf(w01, x, cb0));
                float c1 = fmaf(w10, sc_, fmaf(w11, x, cb1));
                float e1 = exp2f((c1 - c0) * L2E);
                float o0 = fast_rcp(1.f + e1);
                orow[col] = make_float2(o0, 1.f - o0);
            }
        }
    }
}

// ---------------------------------------------------------------------------
extern "C" void kernel_launch(void* const* d_in, const int* in_sizes, int n_in,
                              void* d_out, int out_size, void* d_ws, size_t ws_size,
                              hipStream_t stream)
{
    (void)in_sizes; (void)n_in; (void)out_size; (void)ws_size;
    const float* t     = (const float*)d_in[0];
    const float* ej    = (const float*)d_in[1];
    const float* xt    = (const float*)d_in[2];
    const float* Wq    = (const float*)d_in[3];
    const float* Wk    = (const float*)d_in[4];
    const float* Wv    = (const float*)d_in[5];
    const float* Wc    = (const float*)d_in[6];
    const float* bc    = (const float*)d_in[7];
    const float* convw = (const float*)d_in[8];
    const float* convb = (const float*)d_in[9];
    const float* tW1   = (const float*)d_in[10];
    const float* tb1   = (const float*)d_in[11];
    const float* tW2   = (const float*)d_in[12];
    const float* tb2   = (const float*)d_in[13];
    float* out = (float*)d_out;

    const size_t SZ = (size_t)B_ * N_ * 1024;
    float* ws = (float*)d_ws;
    float* temb = ws;                    // 8192 f32
    float* h1T  = ws + 8192;             // 4096 f32
    unsigned short* ej_bf = (unsigned short*)(ws + 8192 + 4096);
    unsigned short* MH_bf = ej_bf + SZ;
    unsigned short* Wq_bf = MH_bf + SZ;
    unsigned short* Wk_bf = Wq_bf + (size_t)E_ * 1024;
    unsigned short* Wv_bf = Wk_bf + (size_t)E_ * 1024;
    unsigned short* Wc_bf = Wv_bf + (size_t)E_ * 1024;

    unsigned short* Qb = (unsigned short*)d_out;  // Q|K|V|O bf16 = 64MB exactly
    unsigned short* Kb = Qb + SZ;
    unsigned short* Vb = Kb + SZ;
    unsigned short* Ob = Vb + SZ;

    cvt_fused<<<dim3(12416), dim3(256), 0, stream>>>(
        ej, Wq, Wk, Wv, Wc, ej_bf, Wq_bf, Wk_bf, Wv_bf, Wc_bf,
        t, tW1, tb1, h1T);
    temb2_kernel<<<dim3(256), dim3(256), 0, stream>>>(h1T, tW2, tb2, temb);

    dim3 gblk(256);
    qkv_gemm<<<dim3(1536), gblk, 0, stream>>>(
        ej_bf, Wq_bf, Wk_bf, Wv_bf, Qb, Kb, Vb);

    attn_mfma<<<dim3(512), gblk, 0, stream>>>(Qb, Kb, Vb, Ob);

    outproj_gemm<<<dim3(1024), gblk, 0, stream>>>(Ob, Wc_bf, MH_bf, bc, temb);

    score_bf16<<<dim3(1024), gblk, 0, stream>>>(
        MH_bf, ej_bf, xt, convw, convb, out);
}

// Round 13
// 202.372 us; speedup vs baseline: 1.0358x; 1.0358x over previous
//
#include <hip/hip_runtime.h>
#include <hip/hip_bf16.h>
#include <math.h>

#define B_ 8
#define N_ 1024
#define E_ 1024
#define H_ 16
#define D_ 64

typedef __attribute__((ext_vector_type(8))) short short8;
typedef __attribute__((ext_vector_type(4))) float f32x4;

static __device__ __forceinline__ unsigned short f2bf(float f) {
    __hip_bfloat16 h = __float2bfloat16(f);
    return __builtin_bit_cast(unsigned short, h);
}
static __device__ __forceinline__ unsigned int cvtpk_bf16(float a, float b) {
    unsigned int r;
    asm("v_cvt_pk_bf16_f32 %0, %1, %2" : "=v"(r) : "v"(a), "v"(b));
    return r;  // low16 = bf16(a), high16 = bf16(b)
}
static __device__ __forceinline__ float fast_rcp(float x) {
    float r;
    asm("v_rcp_f32 %0, %1" : "=v"(r) : "v"(x));
    return r;  // ~1 ulp
}
static __device__ __forceinline__ void gld_lds16(const void* g, void* l) {
    __builtin_amdgcn_global_load_lds(
        (const __attribute__((address_space(1))) unsigned int*)g,
        (__attribute__((address_space(3))) unsigned int*)l, 16, 0, 0);
}

// ---------------------------------------------------------------------------
// Fused fp32->bf16 conversions + temb layer 1, flat grid (verified round 11)
// ---------------------------------------------------------------------------
__global__ __launch_bounds__(256) void cvt_fused(
    const float* __restrict__ ej, const float* __restrict__ w0,
    const float* __restrict__ w1, const float* __restrict__ w2,
    const float* __restrict__ w3,
    unsigned short* __restrict__ ejd, unsigned short* __restrict__ d0,
    unsigned short* __restrict__ d1, unsigned short* __restrict__ d2,
    unsigned short* __restrict__ d3,
    const float* __restrict__ t, const float* __restrict__ tW1,
    const float* __restrict__ tb1, float* __restrict__ h1T)
{
    const int gid = blockIdx.x;
    const int tid = threadIdx.x;
    if (gid < 12288) {
        const float* s; unsigned short* d; int i;
        if (gid < 8192) {
            s = ej; d = ejd; i = (gid * 256 + tid) * 4;
        } else {
            int w = (gid - 8192) >> 10;
            s = w == 0 ? w0 : (w == 1 ? w1 : (w == 2 ? w2 : w3));
            d = w == 0 ? d0 : (w == 1 ? d1 : (w == 2 ? d2 : d3));
            i = (((gid - 8192) & 1023) * 256 + tid) * 4;
        }
        float4 v = *(const float4*)(s + i);
        *(ushort4*)(d + i) = make_ushort4(f2bf(v.x), f2bf(v.y), f2bf(v.z), f2bf(v.w));
        return;
    }
    const int wv = tid >> 6, lane = tid & 63;
    const int j = (gid - 12288) * 4 + wv;  // 0..511
    float tv[8];
#pragma unroll
    for (int b = 0; b < 8; ++b) tv[b] = t[b];
    const float* w = tW1 + j * 1024;
    float acc[8];
#pragma unroll
    for (int b = 0; b < 8; ++b) acc[b] = 0.f;
    const float kLog = 9.210340371976184f;
    for (int e = lane; e < 1024; e += 64) {
        float we = w[e];
        int ef = e & 511;
        float freq = __expf(-kLog * (float)ef * (1.0f / 512.0f));
        if (e < 512) {
#pragma unroll
            for (int b = 0; b < 8; ++b) acc[b] = fmaf(we, __cosf(tv[b] * freq), acc[b]);
        } else {
#pragma unroll
            for (int b = 0; b < 8; ++b) acc[b] = fmaf(we, __sinf(tv[b] * freq), acc[b]);
        }
    }
#pragma unroll
    for (int off = 32; off > 0; off >>= 1)
#pragma unroll
        for (int b = 0; b < 8; ++b) acc[b] += __shfl_xor(acc[b], off, 64);
    if (lane == 0) {
        float bias = tb1[j];
#pragma unroll
        for (int b = 0; b < 8; ++b) h1T[j * 8 + b] = fmaxf(acc[b] + bias, 0.f);
    }
}

// ---------------------------------------------------------------------------
// 2-phase double-buffered bf16 MFMA K-loop, 128x128 tile (verified: 757 TF)
// ---------------------------------------------------------------------------
static __device__ __forceinline__ void gemm_loop(
    const unsigned short* __restrict__ A, const unsigned short* __restrict__ Bm,
    int m0, int n0, int K,
    unsigned short* As0, unsigned short* As1,
    unsigned short* Bs0, unsigned short* Bs1,
    f32x4 acc[4][4])
{
    const int tid = threadIdx.x;
    const int wave = tid >> 6, lane = tid & 63;
    const int wm = wave >> 1, wn = wave & 1;
    const int sr = lane >> 2, sc = (lane & 3) * 8;
    const unsigned short* Ag0 = A + (size_t)(m0 + wave * 16 + sr) * K + sc;
    const unsigned short* Ag1 = A + (size_t)(m0 + 64 + wave * 16 + sr) * K + sc;
    const unsigned short* Bg0 = Bm + (size_t)(n0 + wave * 16 + sr) * K + sc;
    const unsigned short* Bg1 = Bm + (size_t)(n0 + 64 + wave * 16 + sr) * K + sc;

    const f32x4 zero = {0.f, 0.f, 0.f, 0.f};
#pragma unroll
    for (int i = 0; i < 4; ++i)
#pragma unroll
        for (int j = 0; j < 4; ++j) acc[i][j] = zero;

    gld_lds16(Ag0, As0 + wave * 512);
    gld_lds16(Ag1, As0 + (wave + 4) * 512);
    gld_lds16(Bg0, Bs0 + wave * 512);
    gld_lds16(Bg1, Bs0 + (wave + 4) * 512);
    __syncthreads();

    const int fr = lane & 15, fq = (lane >> 4) * 8;
    int cur = 0;
    for (int k0 = 0; k0 < K; k0 += 32) {
        const unsigned short* sA = cur ? As1 : As0;
        const unsigned short* sB = cur ? Bs1 : Bs0;
        unsigned short* dA = cur ? As0 : As1;
        unsigned short* dB = cur ? Bs0 : Bs1;
        if (k0 + 32 < K) {
            gld_lds16(Ag0 + k0 + 32, dA + wave * 512);
            gld_lds16(Ag1 + k0 + 32, dA + (wave + 4) * 512);
            gld_lds16(Bg0 + k0 + 32, dB + wave * 512);
            gld_lds16(Bg1 + k0 + 32, dB + (wave + 4) * 512);
        }
        short8 af[4], bf[4];
#pragma unroll
        for (int i = 0; i < 4; ++i) {
            af[i] = *(const short8*)&sA[(wm * 64 + i * 16 + fr) * 32 + fq];
            bf[i] = *(const short8*)&sB[(wn * 64 + i * 16 + fr) * 32 + fq];
        }
#pragma unroll
        for (int i = 0; i < 4; ++i)
#pragma unroll
            for (int j = 0; j < 4; ++j)
                acc[i][j] = __builtin_amdgcn_mfma_f32_16x16x32_bf16(
                    af[i], bf[j], acc[i][j], 0, 0, 0);
        __syncthreads();
        cur ^= 1;
    }
}

// ---------------------------------------------------------------------------
// 2-phase double-buffered bf16 MFMA K-loop, 64x128 tile (verified)
// ---------------------------------------------------------------------------
static __device__ __forceinline__ void gemm_loop64(
    const unsigned short* __restrict__ A, const unsigned short* __restrict__ Bm,
    int m0, int n0, int K,
    unsigned short* As0, unsigned short* As1,
    unsigned short* Bs0, unsigned short* Bs1,
    f32x4 acc[2][4])
{
    const int tid = threadIdx.x;
    const int wave = tid >> 6, lane = tid & 63;
    const int wm = wave >> 1, wn = wave & 1;
    const int sr = lane >> 2, sc = (lane & 3) * 8;
    const unsigned short* Ag0 = A + (size_t)(m0 + wave * 16 + sr) * K + sc;
    const unsigned short* Bg0 = Bm + (size_t)(n0 + wave * 16 + sr) * K + sc;
    const unsigned short* Bg1 = Bm + (size_t)(n0 + 64 + wave * 16 + sr) * K + sc;

    const f32x4 zero = {0.f, 0.f, 0.f, 0.f};
#pragma unroll
    for (int i = 0; i < 2; ++i)
#pragma unroll
        for (int j = 0; j < 4; ++j) acc[i][j] = zero;

    gld_lds16(Ag0, As0 + wave * 512);
    gld_lds16(Bg0, Bs0 + wave * 512);
    gld_lds16(Bg1, Bs0 + (wave + 4) * 512);
    __syncthreads();

    const int fr = lane & 15, fq = (lane >> 4) * 8;
    int cur = 0;
    for (int k0 = 0; k0 < K; k0 += 32) {
        const unsigned short* sA = cur ? As1 : As0;
        const unsigned short* sB = cur ? Bs1 : Bs0;
        unsigned short* dA = cur ? As0 : As1;
        unsigned short* dB = cur ? Bs0 : Bs1;
        if (k0 + 32 < K) {
            gld_lds16(Ag0 + k0 + 32, dA + wave * 512);
            gld_lds16(Bg0 + k0 + 32, dB + wave * 512);
            gld_lds16(Bg1 + k0 + 32, dB + (wave + 4) * 512);
        }
        short8 af[2], bf[4];
#pragma unroll
        for (int i = 0; i < 2; ++i)
            af[i] = *(const short8*)&sA[(wm * 32 + i * 16 + fr) * 32 + fq];
#pragma unroll
        for (int j = 0; j < 4; ++j)
            bf[j] = *(const short8*)&sB[(wn * 64 + j * 16 + fr) * 32 + fq];
#pragma unroll
        for (int i = 0; i < 2; ++i)
#pragma unroll
            for (int j = 0; j < 4; ++j)
                acc[i][j] = __builtin_amdgcn_mfma_f32_16x16x32_bf16(
                    af[i], bf[j], acc[i][j], 0, 0, 0);
        __syncthreads();
        cur ^= 1;
    }
}

// ---------------------------------------------------------------------------
// fused Q/K/V projection (blocks 0..1535, 128x128 tile, XCD-swizzled) +
// temb layer 2 (blocks 1536..1791) folded into the same dispatch.
// temb2's input h1T comes from the prior cvt dispatch; its output temb is
// consumed by the later outproj dispatch -> no intra-grid dependency.
// ---------------------------------------------------------------------------
__global__ __launch_bounds__(256) void qkv_gemm(
    const unsigned short* __restrict__ A,
    const unsigned short* __restrict__ W0, const unsigned short* __restrict__ W1,
    const unsigned short* __restrict__ W2,
    unsigned short* __restrict__ C0, unsigned short* __restrict__ C1,
    unsigned short* __restrict__ C2,
    const float* __restrict__ h1T, const float* __restrict__ tW2,
    const float* __restrict__ tb2, float* __restrict__ temb)
{
    const int orig = blockIdx.x;
    if (orig >= 1536) {  // ---- temb layer 2 role ----
        const int wv = threadIdx.x >> 6, lane = threadIdx.x & 63;
        const int e2 = (orig - 1536) * 4 + wv;  // 0..1023
        const float* w = tW2 + e2 * 512;
        float acc[8];
#pragma unroll
        for (int b = 0; b < 8; ++b) acc[b] = 0.f;
        for (int j = lane; j < 512; j += 64) {
            float wv_ = w[j];
            const float* hp = h1T + j * 8;
#pragma unroll
            for (int b = 0; b < 8; ++b) acc[b] = fmaf(hp[b], wv_, acc[b]);
        }
#pragma unroll
        for (int off = 32; off > 0; off >>= 1)
#pragma unroll
            for (int b = 0; b < 8; ++b) acc[b] += __shfl_xor(acc[b], off, 64);
        if (lane == 0) {
            float bias = tb2[e2];
#pragma unroll
            for (int b = 0; b < 8; ++b) temb[b * 1024 + e2] = acc[b] + bias;
        }
        return;
    }
    // ---- GEMM role ----
    __shared__ unsigned short As0[128 * 32], As1[128 * 32];
    __shared__ unsigned short Bs0[128 * 32], Bs1[128 * 32];
    const int sw = (orig & 7) * 192 + (orig >> 3);
    const int z = sw / 512, r = sw & 511;
    const int m0 = (r >> 3) * 128, n0 = (r & 7) * 128;
    const unsigned short* W = z == 0 ? W0 : (z == 1 ? W1 : W2);
    unsigned short* C = z == 0 ? C0 : (z == 1 ? C1 : C2);

    f32x4 acc[4][4];
    gemm_loop(A, W, m0, n0, 1024, As0, As1, Bs0, Bs1, acc);

    const int lane = threadIdx.x & 63, wave = threadIdx.x >> 6;
    const int wm = wave >> 1, wn = wave & 1;
    const int fr = lane & 15, fq4 = (lane >> 4) * 4;
#pragma unroll
    for (int i = 0; i < 4; ++i) {
        int row = m0 + wm * 64 + i * 16 + fq4;
#pragma unroll
        for (int j = 0; j < 4; ++j) {
            int col = n0 + wn * 64 + j * 16 + fr;
#pragma unroll
            for (int rr = 0; rr < 4; ++rr)
                C[(size_t)(row + rr) * 1024 + col] = f2bf(acc[i][j][rr]);
        }
    }
}

// out-projection (+bias+temb), 64x128 tile, grid(1024) XCD-swizzled
__global__ __launch_bounds__(256) void outproj_gemm(
    const unsigned short* __restrict__ A, const unsigned short* __restrict__ Bm,
    unsigned short* __restrict__ C,
    const float* __restrict__ bias, const float* __restrict__ temb)
{
    __shared__ unsigned short As0[64 * 32], As1[64 * 32];
    __shared__ unsigned short Bs0[128 * 32], Bs1[128 * 32];
    const int orig = blockIdx.x;
    const int sw = (orig & 7) * 128 + (orig >> 3);
    const int mt = sw >> 3, n0 = (sw & 7) * 128;
    const int m0 = mt * 64;

    f32x4 acc[2][4];
    gemm_loop64(A, Bm, m0, n0, 1024, As0, As1, Bs0, Bs1, acc);

    const int lane = threadIdx.x & 63, wave = threadIdx.x >> 6;
    const int wm = wave >> 1, wn = wave & 1;
    const int fr = lane & 15, fq4 = (lane >> 4) * 4;
    const int bb = m0 >> 10;
#pragma unroll
    for (int i = 0; i < 2; ++i) {
        int row = m0 + wm * 32 + i * 16 + fq4;
#pragma unroll
        for (int j = 0; j < 4; ++j) {
            int col = n0 + wn * 64 + j * 16 + fr;
            float epi = bias[col] + temb[bb * 1024 + col];
#pragma unroll
            for (int rr = 0; rr < 4; ++rr)
                C[(size_t)(row + rr) * 1024 + col] = f2bf(acc[i][j][rr] + epi);
        }
    }
}

// ---------------------------------------------------------------------------
// MFMA flash attention, qt=4 (round-11 verified config: single-buffer K/V,
// T14 register prefetch).  Swapped-operand, P in registers (kv permutation),
// bounded-score softmax, l via ones-row on matrix pipe.  grid 512.
// ---------------------------------------------------------------------------
__global__ __launch_bounds__(256, 2) void attn_mfma(
    const unsigned short* __restrict__ Q, const unsigned short* __restrict__ K,
    const unsigned short* __restrict__ V, unsigned short* __restrict__ O)
{
    __shared__ __align__(16) unsigned short Ks[64 * 72];
    __shared__ __align__(16) unsigned short Vts[80 * 72];  // rows 64..79 = ones/0
    const int tid = threadIdx.x;
    const int wq = tid >> 6, lane = tid & 63;
    const int lo = lane & 15, hi = lane >> 4;
    const int id = blockIdx.x;                 // 512 blocks
    const int sw = (id & 7) * 64 + (id >> 3);  // bijective XCD swizzle
    const int q0 = (sw & 3) * 256;
    const int h = (sw >> 2) & 15, b = sw >> 6;
    const size_t base = ((size_t)b * N_) * 1024 + h * 64;

    for (int i = tid; i < 16 * 64; i += 256) {
        int rr = i >> 6, cc = i & 63;
        Vts[(64 + rr) * 72 + cc] = (rr == 0) ? (unsigned short)0x3F80 : (unsigned short)0;
    }
    __syncthreads();
    short8 vb4[2];   // constant ones-row B-frag
#pragma unroll
    for (int k2 = 0; k2 < 2; ++k2)
        vb4[k2] = *(const short8*)&Vts[(64 + lo) * 72 + hi * 8 + k2 * 32];

    short8 aq[4][2];
#pragma unroll
    for (int qt = 0; qt < 4; ++qt)
#pragma unroll
        for (int ks = 0; ks < 2; ++ks)
            aq[qt][ks] = *(const short8*)(Q + base +
                (size_t)(q0 + wq * 64 + qt * 16 + lo) * 1024 + hi * 8 + ks * 32);

    f32x4 o_[4][5];   // [qt][db]; db=4 is the l-row
    const f32x4 zero = {0.f, 0.f, 0.f, 0.f};
#pragma unroll
    for (int qt = 0; qt < 4; ++qt)
#pragma unroll
        for (int db = 0; db < 5; ++db) o_[qt][db] = zero;

    const int kr = tid >> 2, ku = (tid & 3) * 16;
    const unsigned short* Kg = K + base + (size_t)kr * 1024 + ku;
    const int vkv = (tid & 31) * 2, vd = (tid >> 5) * 8;
    const int scol = (vkv & 0x23) | ((vkv & 0x0C) << 1) | ((vkv & 0x10) >> 2);
    const unsigned short* Vg = V + base + (size_t)vkv * 1024 + vd;

    short8 kl0 = *(const short8*)(Kg);
    short8 kl1 = *(const short8*)(Kg + 8);
    short8 vla = *(const short8*)(Vg);
    short8 vlb = *(const short8*)(Vg + 1024);

    const float cexp = 0.1803368801111204f;  // log2(e)/8

    for (int kt = 0; kt < N_; kt += 64) {
        __syncthreads();
        *(short8*)&Ks[kr * 72 + ku] = kl0;
        *(short8*)&Ks[kr * 72 + ku + 8] = kl1;
#pragma unroll
        for (int i = 0; i < 8; ++i) {
            unsigned int pv = (unsigned int)(unsigned short)vla[i] |
                              ((unsigned int)(unsigned short)vlb[i] << 16);
            *(unsigned int*)&Vts[(vd + i) * 72 + scol] = pv;
        }
        __syncthreads();
        if (kt + 64 < N_) {  // T14 prefetch under compute
            kl0 = *(const short8*)(Kg + (size_t)(kt + 64) * 1024);
            kl1 = *(const short8*)(Kg + (size_t)(kt + 64) * 1024 + 8);
            vla = *(const short8*)(Vg + (size_t)(kt + 64) * 1024);
            vlb = *(const short8*)(Vg + (size_t)(kt + 64) * 1024 + 1024);
        }

        short8 kb[4][2], vb[4][2];
#pragma unroll
        for (int jk = 0; jk < 4; ++jk)
#pragma unroll
            for (int ks = 0; ks < 2; ++ks)
                kb[jk][ks] = *(const short8*)&Ks[(16 * jk + lo) * 72 + hi * 8 + ks * 32];
#pragma unroll
        for (int db = 0; db < 4; ++db)
#pragma unroll
            for (int k2 = 0; k2 < 2; ++k2)
                vb[db][k2] = *(const short8*)&Vts[(16 * db + lo) * 72 +
                                                  hi * 8 + k2 * 32];

#pragma unroll
        for (int qt = 0; qt < 4; ++qt) {
            f32x4 s[4];
            __builtin_amdgcn_s_setprio(1);
#pragma unroll
            for (int jk = 0; jk < 4; ++jk) {
                s[jk] = __builtin_amdgcn_mfma_f32_16x16x32_bf16(
                    kb[jk][0], aq[qt][0], zero, 0, 0, 0);
                s[jk] = __builtin_amdgcn_mfma_f32_16x16x32_bf16(
                    kb[jk][1], aq[qt][1], s[jk], 0, 0, 0);
            }
            __builtin_amdgcn_s_setprio(0);
#pragma unroll
            for (int jk = 0; jk < 4; ++jk)
#pragma unroll
                for (int rr = 0; rr < 4; ++rr)
                    s[jk][rr] = exp2f(s[jk][rr] * cexp);
            unsigned int pw[8];
#pragma unroll
            for (int jk = 0; jk < 4; ++jk) {
                pw[2 * jk] = cvtpk_bf16(s[jk][0], s[jk][1]);
                pw[2 * jk + 1] = cvtpk_bf16(s[jk][2], s[jk][3]);
            }
            uint4 pa0 = make_uint4(pw[0], pw[1], pw[2], pw[3]);
            uint4 pa1 = make_uint4(pw[4], pw[5], pw[6], pw[7]);
            short8 pA = __builtin_bit_cast(short8, pa0);
            short8 pB = __builtin_bit_cast(short8, pa1);

            __builtin_amdgcn_s_setprio(1);
#pragma unroll
            for (int db = 0; db < 4; ++db) {
                o_[qt][db] = __builtin_amdgcn_mfma_f32_16x16x32_bf16(
                    vb[db][0], pA, o_[qt][db], 0, 0, 0);
                o_[qt][db] = __builtin_amdgcn_mfma_f32_16x16x32_bf16(
                    vb[db][1], pB, o_[qt][db], 0, 0, 0);
            }
            o_[qt][4] = __builtin_amdgcn_mfma_f32_16x16x32_bf16(
                vb4[0], pA, o_[qt][4], 0, 0, 0);
            o_[qt][4] = __builtin_amdgcn_mfma_f32_16x16x32_bf16(
                vb4[1], pB, o_[qt][4], 0, 0, 0);
            __builtin_amdgcn_s_setprio(0);
        }
    }

#pragma unroll
    for (int qt = 0; qt < 4; ++qt) {
        float lsum = __shfl(o_[qt][4][0], lo, 64);
        float inv = fast_rcp(lsum);
        const size_t rb = base + (size_t)(q0 + wq * 64 + qt * 16 + lo) * 1024;
#pragma unroll
        for (int db = 0; db < 4; ++db) {
            *(ushort4*)(O + rb + 16 * db + 4 * hi) = make_ushort4(
                f2bf(o_[qt][db][0] * inv), f2bf(o_[qt][db][1] * inv),
                f2bf(o_[qt][db][2] * inv), f2bf(o_[qt][db][3] * inv));
        }
    }
}

// ---------------------------------------------------------------------------
// Score GEMM + tanh clip + 1x1 conv + 2-way softmax.  64x128 tile,
// grid(1024) XCD-swizzled.  Fast transcendentals + v_rcp.
// ---------------------------------------------------------------------------
__global__ __launch_bounds__(256) void score_bf16(
    const unsigned short* __restrict__ MH, const unsigned short* __restrict__ EJ,
    const float* __restrict__ xt, const float* __restrict__ convw,
    const float* __restrict__ convb, float* __restrict__ out)
{
    __shared__ unsigned short As0[64 * 32], As1[64 * 32];
    __shared__ unsigned short Bs0[128 * 32], Bs1[128 * 32];
    const int orig = blockIdx.x;
    const int sw = (orig & 7) * 128 + (orig >> 3);
    const int bz = sw >> 7;
    const int m0 = ((sw >> 3) & 15) * 64, n0 = (sw & 7) * 128;
    const unsigned short* A = MH + (size_t)bz * N_ * E_;
    const unsigned short* Bm = EJ + (size_t)bz * N_ * E_;

    f32x4 acc[2][4];
    gemm_loop64(A, Bm, m0, n0, 1024, As0, As1, Bs0, Bs1, acc);

    const int lane = threadIdx.x & 63, wave = threadIdx.x >> 6;
    const int wm = wave >> 1, wn = wave & 1;
    const int fr = lane & 15, fq4 = (lane >> 4) * 4;
    const float w00 = convw[0], w01 = convw[1], w10 = convw[2], w11 = convw[3];
    const float cb0 = convb[0], cb1 = convb[1];
    const float L2E = 1.4426950408889634f;
    const float kT = -2.f * L2E * 0.03125f;
#pragma unroll
    for (int i = 0; i < 2; ++i) {
#pragma unroll
        for (int rr = 0; rr < 4; ++rr) {
            int row = m0 + wm * 32 + i * 16 + fq4 + rr;
            const float* xrow = xt + ((size_t)bz * N_ + row) * N_;
            float2* orow = (float2*)(out + (((size_t)bz * N_ + row) * N_) * 2);
#pragma unroll
            for (int j = 0; j < 4; ++j) {
                int col = n0 + wn * 64 + j * 16 + fr;
                float e = exp2f(acc[i][j][rr] * kT);
                float sc_ = fmaf(20.f, fast_rcp(1.f + e), -10.f);  // 10*tanh
                float x = xrow[col];
                float c0 = fmaf(w00, sc_, fmaf(w01, x, cb0));
                float c1 = fmaf(w10, sc_, fmaf(w11, x, cb1));
                float e1 = exp2f((c1 - c0) * L2E);
                float o0 = fast_rcp(1.f + e1);
                orow[col] = make_float2(o0, 1.f - o0);
            }
        }
    }
}

// ---------------------------------------------------------------------------
extern "C" void kernel_launch(void* const* d_in, const int* in_sizes, int n_in,
                              void* d_out, int out_size, void* d_ws, size_t ws_size,
                              hipStream_t stream)
{
    (void)in_sizes; (void)n_in; (void)out_size; (void)ws_size;
    const float* t     = (const float*)d_in[0];
    const float* ej    = (const float*)d_in[1];
    const float* xt    = (const float*)d_in[2];
    const float* Wq    = (const float*)d_in[3];
    const float* Wk    = (const float*)d_in[4];
    const float* Wv    = (const float*)d_in[5];
    const float* Wc    = (const float*)d_in[6];
    const float* bc    = (const float*)d_in[7];
    const float* convw = (const float*)d_in[8];
    const float* convb = (const float*)d_in[9];
    const float* tW1   = (const float*)d_in[10];
    const float* tb1   = (const float*)d_in[11];
    const float* tW2   = (const float*)d_in[12];
    const float* tb2   = (const float*)d_in[13];
    float* out = (float*)d_out;

    const size_t SZ = (size_t)B_ * N_ * 1024;
    float* ws = (float*)d_ws;
    float* temb = ws;                    // 8192 f32
    float* h1T  = ws + 8192;             // 4096 f32
    unsigned short* ej_bf = (unsigned short*)(ws + 8192 + 4096);
    unsigned short* MH_bf = ej_bf + SZ;
    unsigned short* Wq_bf = MH_bf + SZ;
    unsigned short* Wk_bf = Wq_bf + (size_t)E_ * 1024;
    unsigned short* Wv_bf = Wk_bf + (size_t)E_ * 1024;
    unsigned short* Wc_bf = Wv_bf + (size_t)E_ * 1024;

    unsigned short* Qb = (unsigned short*)d_out;  // Q|K|V|O bf16 = 64MB exactly
    unsigned short* Kb = Qb + SZ;
    unsigned short* Vb = Kb + SZ;
    unsigned short* Ob = Vb + SZ;

    cvt_fused<<<dim3(12416), dim3(256), 0, stream>>>(
        ej, Wq, Wk, Wv, Wc, ej_bf, Wq_bf, Wk_bf, Wv_bf, Wc_bf,
        t, tW1, tb1, h1T);

    dim3 gblk(256);
    qkv_gemm<<<dim3(1792), gblk, 0, stream>>>(
        ej_bf, Wq_bf, Wk_bf, Wv_bf, Qb, Kb, Vb, h1T, tW2, tb2, temb);

    attn_mfma<<<dim3(512), gblk, 0, stream>>>(Qb, Kb, Vb, Ob);

    outproj_gemm<<<dim3(1024), gblk, 0, stream>>>(Ob, Wc_bf, MH_bf, bc, temb);

    score_bf16<<<dim3(1024), gblk, 0, stream>>>(
        MH_bf, ej_bf, xt, convw, convb, out);
}

// Round 14
// 198.519 us; speedup vs baseline: 1.0559x; 1.0194x over previous
//
#include <hip/hip_runtime.h>
#include <hip/hip_bf16.h>
#include <math.h>

#define B_ 8
#define N_ 1024
#define E_ 1024
#define H_ 16
#define D_ 64

typedef __attribute__((ext_vector_type(8))) short short8;
typedef __attribute__((ext_vector_type(4))) float f32x4;

static __device__ __forceinline__ unsigned short f2bf(float f) {
    __hip_bfloat16 h = __float2bfloat16(f);
    return __builtin_bit_cast(unsigned short, h);
}
static __device__ __forceinline__ unsigned int cvtpk_bf16(float a, float b) {
    unsigned int r;
    asm("v_cvt_pk_bf16_f32 %0, %1, %2" : "=v"(r) : "v"(a), "v"(b));
    return r;  // low16 = bf16(a), high16 = bf16(b)
}
static __device__ __forceinline__ float fast_rcp(float x) {
    float r;
    asm("v_rcp_f32 %0, %1" : "=v"(r) : "v"(x));
    return r;  // ~1 ulp
}
static __device__ __forceinline__ void gld_lds16(const void* g, void* l) {
    __builtin_amdgcn_global_load_lds(
        (const __attribute__((address_space(1))) unsigned int*)g,
        (__attribute__((address_space(3))) unsigned int*)l, 16, 0, 0);
}

// ---------------------------------------------------------------------------
// Fused temb layer 1 (blocks 0..127, FIRST so the heavy trig runs concurrent
// with the conversions, not as a tail) + fp32->bf16 conversions:
//   blocks [128,8320)    : ej (8M elems, 4/thread)
//   blocks [8320,12416)  : weights Wq/Wk/Wv/Wc (1M elems each)
// ---------------------------------------------------------------------------
__global__ __launch_bounds__(256) void cvt_fused(
    const float* __restrict__ ej, const float* __restrict__ w0,
    const float* __restrict__ w1, const float* __restrict__ w2,
    const float* __restrict__ w3,
    unsigned short* __restrict__ ejd, unsigned short* __restrict__ d0,
    unsigned short* __restrict__ d1, unsigned short* __restrict__ d2,
    unsigned short* __restrict__ d3,
    const float* __restrict__ t, const float* __restrict__ tW1,
    const float* __restrict__ tb1, float* __restrict__ h1T)
{
    const int gid = blockIdx.x;
    const int tid = threadIdx.x;
    if (gid >= 128) {
        const int cg = gid - 128;
        const float* s; unsigned short* d; int i;
        if (cg < 8192) {
            s = ej; d = ejd; i = (cg * 256 + tid) * 4;
        } else {
            int w = (cg - 8192) >> 10;
            s = w == 0 ? w0 : (w == 1 ? w1 : (w == 2 ? w2 : w3));
            d = w == 0 ? d0 : (w == 1 ? d1 : (w == 2 ? d2 : d3));
            i = (((cg - 8192) & 1023) * 256 + tid) * 4;
        }
        float4 v = *(const float4*)(s + i);
        *(ushort4*)(d + i) = make_ushort4(f2bf(v.x), f2bf(v.y), f2bf(v.z), f2bf(v.w));
        return;
    }
    // ---- temb layer 1 role (blocks 0..127) ----
    const int wv = tid >> 6, lane = tid & 63;
    const int j = gid * 4 + wv;  // 0..511
    float tv[8];
#pragma unroll
    for (int b = 0; b < 8; ++b) tv[b] = t[b];
    const float* w = tW1 + j * 1024;
    float acc[8];
#pragma unroll
    for (int b = 0; b < 8; ++b) acc[b] = 0.f;
    const float kLog = 9.210340371976184f;
    for (int e = lane; e < 1024; e += 64) {
        float we = w[e];
        int ef = e & 511;
        float freq = __expf(-kLog * (float)ef * (1.0f / 512.0f));
        if (e < 512) {
#pragma unroll
            for (int b = 0; b < 8; ++b) acc[b] = fmaf(we, __cosf(tv[b] * freq), acc[b]);
        } else {
#pragma unroll
            for (int b = 0; b < 8; ++b) acc[b] = fmaf(we, __sinf(tv[b] * freq), acc[b]);
        }
    }
#pragma unroll
    for (int off = 32; off > 0; off >>= 1)
#pragma unroll
        for (int b = 0; b < 8; ++b) acc[b] += __shfl_xor(acc[b], off, 64);
    if (lane == 0) {
        float bias = tb1[j];
#pragma unroll
        for (int b = 0; b < 8; ++b) h1T[j * 8 + b] = fmaxf(acc[b] + bias, 0.f);
    }
}

// ---------------------------------------------------------------------------
// 2-phase double-buffered bf16 MFMA K-loop, 128x128 tile (verified: 757 TF)
// ---------------------------------------------------------------------------
static __device__ __forceinline__ void gemm_loop(
    const unsigned short* __restrict__ A, const unsigned short* __restrict__ Bm,
    int m0, int n0, int K,
    unsigned short* As0, unsigned short* As1,
    unsigned short* Bs0, unsigned short* Bs1,
    f32x4 acc[4][4])
{
    const int tid = threadIdx.x;
    const int wave = tid >> 6, lane = tid & 63;
    const int wm = wave >> 1, wn = wave & 1;
    const int sr = lane >> 2, sc = (lane & 3) * 8;
    const unsigned short* Ag0 = A + (size_t)(m0 + wave * 16 + sr) * K + sc;
    const unsigned short* Ag1 = A + (size_t)(m0 + 64 + wave * 16 + sr) * K + sc;
    const unsigned short* Bg0 = Bm + (size_t)(n0 + wave * 16 + sr) * K + sc;
    const unsigned short* Bg1 = Bm + (size_t)(n0 + 64 + wave * 16 + sr) * K + sc;

    const f32x4 zero = {0.f, 0.f, 0.f, 0.f};
#pragma unroll
    for (int i = 0; i < 4; ++i)
#pragma unroll
        for (int j = 0; j < 4; ++j) acc[i][j] = zero;

    gld_lds16(Ag0, As0 + wave * 512);
    gld_lds16(Ag1, As0 + (wave + 4) * 512);
    gld_lds16(Bg0, Bs0 + wave * 512);
    gld_lds16(Bg1, Bs0 + (wave + 4) * 512);
    __syncthreads();

    const int fr = lane & 15, fq = (lane >> 4) * 8;
    int cur = 0;
    for (int k0 = 0; k0 < K; k0 += 32) {
        const unsigned short* sA = cur ? As1 : As0;
        const unsigned short* sB = cur ? Bs1 : Bs0;
        unsigned short* dA = cur ? As0 : As1;
        unsigned short* dB = cur ? Bs0 : Bs1;
        if (k0 + 32 < K) {
            gld_lds16(Ag0 + k0 + 32, dA + wave * 512);
            gld_lds16(Ag1 + k0 + 32, dA + (wave + 4) * 512);
            gld_lds16(Bg0 + k0 + 32, dB + wave * 512);
            gld_lds16(Bg1 + k0 + 32, dB + (wave + 4) * 512);
        }
        short8 af[4], bf[4];
#pragma unroll
        for (int i = 0; i < 4; ++i) {
            af[i] = *(const short8*)&sA[(wm * 64 + i * 16 + fr) * 32 + fq];
            bf[i] = *(const short8*)&sB[(wn * 64 + i * 16 + fr) * 32 + fq];
        }
#pragma unroll
        for (int i = 0; i < 4; ++i)
#pragma unroll
            for (int j = 0; j < 4; ++j)
                acc[i][j] = __builtin_amdgcn_mfma_f32_16x16x32_bf16(
                    af[i], bf[j], acc[i][j], 0, 0, 0);
        __syncthreads();
        cur ^= 1;
    }
}

// ---------------------------------------------------------------------------
// 2-phase double-buffered bf16 MFMA K-loop, 64x128 tile (verified)
// ---------------------------------------------------------------------------
static __device__ __forceinline__ void gemm_loop64(
    const unsigned short* __restrict__ A, const unsigned short* __restrict__ Bm,
    int m0, int n0, int K,
    unsigned short* As0, unsigned short* As1,
    unsigned short* Bs0, unsigned short* Bs1,
    f32x4 acc[2][4])
{
    const int tid = threadIdx.x;
    const int wave = tid >> 6, lane = tid & 63;
    const int wm = wave >> 1, wn = wave & 1;
    const int sr = lane >> 2, sc = (lane & 3) * 8;
    const unsigned short* Ag0 = A + (size_t)(m0 + wave * 16 + sr) * K + sc;
    const unsigned short* Bg0 = Bm + (size_t)(n0 + wave * 16 + sr) * K + sc;
    const unsigned short* Bg1 = Bm + (size_t)(n0 + 64 + wave * 16 + sr) * K + sc;

    const f32x4 zero = {0.f, 0.f, 0.f, 0.f};
#pragma unroll
    for (int i = 0; i < 2; ++i)
#pragma unroll
        for (int j = 0; j < 4; ++j) acc[i][j] = zero;

    gld_lds16(Ag0, As0 + wave * 512);
    gld_lds16(Bg0, Bs0 + wave * 512);
    gld_lds16(Bg1, Bs0 + (wave + 4) * 512);
    __syncthreads();

    const int fr = lane & 15, fq = (lane >> 4) * 8;
    int cur = 0;
    for (int k0 = 0; k0 < K; k0 += 32) {
        const unsigned short* sA = cur ? As1 : As0;
        const unsigned short* sB = cur ? Bs1 : Bs0;
        unsigned short* dA = cur ? As0 : As1;
        unsigned short* dB = cur ? Bs0 : Bs1;
        if (k0 + 32 < K) {
            gld_lds16(Ag0 + k0 + 32, dA + wave * 512);
            gld_lds16(Bg0 + k0 + 32, dB + wave * 512);
            gld_lds16(Bg1 + k0 + 32, dB + (wave + 4) * 512);
        }
        short8 af[2], bf[4];
#pragma unroll
        for (int i = 0; i < 2; ++i)
            af[i] = *(const short8*)&sA[(wm * 32 + i * 16 + fr) * 32 + fq];
#pragma unroll
        for (int j = 0; j < 4; ++j)
            bf[j] = *(const short8*)&sB[(wn * 64 + j * 16 + fr) * 32 + fq];
#pragma unroll
        for (int i = 0; i < 2; ++i)
#pragma unroll
            for (int j = 0; j < 4; ++j)
                acc[i][j] = __builtin_amdgcn_mfma_f32_16x16x32_bf16(
                    af[i], bf[j], acc[i][j], 0, 0, 0);
        __syncthreads();
        cur ^= 1;
    }
}

// ---------------------------------------------------------------------------
// temb layer 2 (blocks 0..255, FIRST — runs concurrent with GEMM, no tail) +
// fused Q/K/V projection (blocks 256..1791, 128x128 tile, XCD-swizzled).
// temb2's input h1T comes from the prior cvt dispatch; its output temb is
// consumed by the later outproj dispatch -> no intra-grid dependency.
// ---------------------------------------------------------------------------
__global__ __launch_bounds__(256) void qkv_gemm(
    const unsigned short* __restrict__ A,
    const unsigned short* __restrict__ W0, const unsigned short* __restrict__ W1,
    const unsigned short* __restrict__ W2,
    unsigned short* __restrict__ C0, unsigned short* __restrict__ C1,
    unsigned short* __restrict__ C2,
    const float* __restrict__ h1T, const float* __restrict__ tW2,
    const float* __restrict__ tb2, float* __restrict__ temb)
{
    const int orig = blockIdx.x;
    if (orig < 256) {  // ---- temb layer 2 role ----
        const int wv = threadIdx.x >> 6, lane = threadIdx.x & 63;
        const int e2 = orig * 4 + wv;  // 0..1023
        const float* w = tW2 + e2 * 512;
        float acc[8];
#pragma unroll
        for (int b = 0; b < 8; ++b) acc[b] = 0.f;
        for (int j = lane; j < 512; j += 64) {
            float wv_ = w[j];
            const float* hp = h1T + j * 8;
#pragma unroll
            for (int b = 0; b < 8; ++b) acc[b] = fmaf(hp[b], wv_, acc[b]);
        }
#pragma unroll
        for (int off = 32; off > 0; off >>= 1)
#pragma unroll
            for (int b = 0; b < 8; ++b) acc[b] += __shfl_xor(acc[b], off, 64);
        if (lane == 0) {
            float bias = tb2[e2];
#pragma unroll
            for (int b = 0; b < 8; ++b) temb[b * 1024 + e2] = acc[b] + bias;
        }
        return;
    }
    // ---- GEMM role ----
    __shared__ unsigned short As0[128 * 32], As1[128 * 32];
    __shared__ unsigned short Bs0[128 * 32], Bs1[128 * 32];
    const int g = orig - 256;  // 0..1535
    const int sw = (g & 7) * 192 + (g >> 3);
    const int z = sw / 512, r = sw & 511;
    const int m0 = (r >> 3) * 128, n0 = (r & 7) * 128;
    const unsigned short* W = z == 0 ? W0 : (z == 1 ? W1 : W2);
    unsigned short* C = z == 0 ? C0 : (z == 1 ? C1 : C2);

    f32x4 acc[4][4];
    gemm_loop(A, W, m0, n0, 1024, As0, As1, Bs0, Bs1, acc);

    const int lane = threadIdx.x & 63, wave = threadIdx.x >> 6;
    const int wm = wave >> 1, wn = wave & 1;
    const int fr = lane & 15, fq4 = (lane >> 4) * 4;
#pragma unroll
    for (int i = 0; i < 4; ++i) {
        int row = m0 + wm * 64 + i * 16 + fq4;
#pragma unroll
        for (int j = 0; j < 4; ++j) {
            int col = n0 + wn * 64 + j * 16 + fr;
#pragma unroll
            for (int rr = 0; rr < 4; ++rr)
                C[(size_t)(row + rr) * 1024 + col] = f2bf(acc[i][j][rr]);
        }
    }
}

// out-projection (+bias+temb), 64x128 tile, grid(1024) XCD-swizzled
__global__ __launch_bounds__(256) void outproj_gemm(
    const unsigned short* __restrict__ A, const unsigned short* __restrict__ Bm,
    unsigned short* __restrict__ C,
    const float* __restrict__ bias, const float* __restrict__ temb)
{
    __shared__ unsigned short As0[64 * 32], As1[64 * 32];
    __shared__ unsigned short Bs0[128 * 32], Bs1[128 * 32];
    const int orig = blockIdx.x;
    const int sw = (orig & 7) * 128 + (orig >> 3);
    const int mt = sw >> 3, n0 = (sw & 7) * 128;
    const int m0 = mt * 64;

    f32x4 acc[2][4];
    gemm_loop64(A, Bm, m0, n0, 1024, As0, As1, Bs0, Bs1, acc);

    const int lane = threadIdx.x & 63, wave = threadIdx.x >> 6;
    const int wm = wave >> 1, wn = wave & 1;
    const int fr = lane & 15, fq4 = (lane >> 4) * 4;
    const int bb = m0 >> 10;
#pragma unroll
    for (int i = 0; i < 2; ++i) {
        int row = m0 + wm * 32 + i * 16 + fq4;
#pragma unroll
        for (int j = 0; j < 4; ++j) {
            int col = n0 + wn * 64 + j * 16 + fr;
            float epi = bias[col] + temb[bb * 1024 + col];
#pragma unroll
            for (int rr = 0; rr < 4; ++rr)
                C[(size_t)(row + rr) * 1024 + col] = f2bf(acc[i][j][rr] + epi);
        }
    }
}

// ---------------------------------------------------------------------------
// MFMA flash attention, qt=4 (round-11 verified config: single-buffer K/V,
// T14 register prefetch).  Swapped-operand, P in registers (kv permutation),
// bounded-score softmax, l via ones-row on matrix pipe.  grid 512.
// ---------------------------------------------------------------------------
__global__ __launch_bounds__(256, 2) void attn_mfma(
    const unsigned short* __restrict__ Q, const unsigned short* __restrict__ K,
    const unsigned short* __restrict__ V, unsigned short* __restrict__ O)
{
    __shared__ __align__(16) unsigned short Ks[64 * 72];
    __shared__ __align__(16) unsigned short Vts[80 * 72];  // rows 64..79 = ones/0
    const int tid = threadIdx.x;
    const int wq = tid >> 6, lane = tid & 63;
    const int lo = lane & 15, hi = lane >> 4;
    const int id = blockIdx.x;                 // 512 blocks
    const int sw = (id & 7) * 64 + (id >> 3);  // bijective XCD swizzle
    const int q0 = (sw & 3) * 256;
    const int h = (sw >> 2) & 15, b = sw >> 6;
    const size_t base = ((size_t)b * N_) * 1024 + h * 64;

    for (int i = tid; i < 16 * 64; i += 256) {
        int rr = i >> 6, cc = i & 63;
        Vts[(64 + rr) * 72 + cc] = (rr == 0) ? (unsigned short)0x3F80 : (unsigned short)0;
    }
    __syncthreads();
    short8 vb4[2];   // constant ones-row B-frag
#pragma unroll
    for (int k2 = 0; k2 < 2; ++k2)
        vb4[k2] = *(const short8*)&Vts[(64 + lo) * 72 + hi * 8 + k2 * 32];

    short8 aq[4][2];
#pragma unroll
    for (int qt = 0; qt < 4; ++qt)
#pragma unroll
        for (int ks = 0; ks < 2; ++ks)
            aq[qt][ks] = *(const short8*)(Q + base +
                (size_t)(q0 + wq * 64 + qt * 16 + lo) * 1024 + hi * 8 + ks * 32);

    f32x4 o_[4][5];   // [qt][db]; db=4 is the l-row
    const f32x4 zero = {0.f, 0.f, 0.f, 0.f};
#pragma unroll
    for (int qt = 0; qt < 4; ++qt)
#pragma unroll
        for (int db = 0; db < 5; ++db) o_[qt][db] = zero;

    const int kr = tid >> 2, ku = (tid & 3) * 16;
    const unsigned short* Kg = K + base + (size_t)kr * 1024 + ku;
    const int vkv = (tid & 31) * 2, vd = (tid >> 5) * 8;
    const int scol = (vkv & 0x23) | ((vkv & 0x0C) << 1) | ((vkv & 0x10) >> 2);
    const unsigned short* Vg = V + base + (size_t)vkv * 1024 + vd;

    short8 kl0 = *(const short8*)(Kg);
    short8 kl1 = *(const short8*)(Kg + 8);
    short8 vla = *(const short8*)(Vg);
    short8 vlb = *(const short8*)(Vg + 1024);

    const float cexp = 0.1803368801111204f;  // log2(e)/8

    for (int kt = 0; kt < N_; kt += 64) {
        __syncthreads();
        *(short8*)&Ks[kr * 72 + ku] = kl0;
        *(short8*)&Ks[kr * 72 + ku + 8] = kl1;
#pragma unroll
        for (int i = 0; i < 8; ++i) {
            unsigned int pv = (unsigned int)(unsigned short)vla[i] |
                              ((unsigned int)(unsigned short)vlb[i] << 16);
            *(unsigned int*)&Vts[(vd + i) * 72 + scol] = pv;
        }
        __syncthreads();
        if (kt + 64 < N_) {  // T14 prefetch under compute
            kl0 = *(const short8*)(Kg + (size_t)(kt + 64) * 1024);
            kl1 = *(const short8*)(Kg + (size_t)(kt + 64) * 1024 + 8);
            vla = *(const short8*)(Vg + (size_t)(kt + 64) * 1024);
            vlb = *(const short8*)(Vg + (size_t)(kt + 64) * 1024 + 1024);
        }

        short8 kb[4][2], vb[4][2];
#pragma unroll
        for (int jk = 0; jk < 4; ++jk)
#pragma unroll
            for (int ks = 0; ks < 2; ++ks)
                kb[jk][ks] = *(const short8*)&Ks[(16 * jk + lo) * 72 + hi * 8 + ks * 32];
#pragma unroll
        for (int db = 0; db < 4; ++db)
#pragma unroll
            for (int k2 = 0; k2 < 2; ++k2)
                vb[db][k2] = *(const short8*)&Vts[(16 * db + lo) * 72 +
                                                  hi * 8 + k2 * 32];

#pragma unroll
        for (int qt = 0; qt < 4; ++qt) {
            f32x4 s[4];
            __builtin_amdgcn_s_setprio(1);
#pragma unroll
            for (int jk = 0; jk < 4; ++jk) {
                s[jk] = __builtin_amdgcn_mfma_f32_16x16x32_bf16(
                    kb[jk][0], aq[qt][0], zero, 0, 0, 0);
                s[jk] = __builtin_amdgcn_mfma_f32_16x16x32_bf16(
                    kb[jk][1], aq[qt][1], s[jk], 0, 0, 0);
            }
            __builtin_amdgcn_s_setprio(0);
#pragma unroll
            for (int jk = 0; jk < 4; ++jk)
#pragma unroll
                for (int rr = 0; rr < 4; ++rr)
                    s[jk][rr] = exp2f(s[jk][rr] * cexp);
            unsigned int pw[8];
#pragma unroll
            for (int jk = 0; jk < 4; ++jk) {
                pw[2 * jk] = cvtpk_bf16(s[jk][0], s[jk][1]);
                pw[2 * jk + 1] = cvtpk_bf16(s[jk][2], s[jk][3]);
            }
            uint4 pa0 = make_uint4(pw[0], pw[1], pw[2], pw[3]);
            uint4 pa1 = make_uint4(pw[4], pw[5], pw[6], pw[7]);
            short8 pA = __builtin_bit_cast(short8, pa0);
            short8 pB = __builtin_bit_cast(short8, pa1);

            __builtin_amdgcn_s_setprio(1);
#pragma unroll
            for (int db = 0; db < 4; ++db) {
                o_[qt][db] = __builtin_amdgcn_mfma_f32_16x16x32_bf16(
                    vb[db][0], pA, o_[qt][db], 0, 0, 0);
                o_[qt][db] = __builtin_amdgcn_mfma_f32_16x16x32_bf16(
                    vb[db][1], pB, o_[qt][db], 0, 0, 0);
            }
            o_[qt][4] = __builtin_amdgcn_mfma_f32_16x16x32_bf16(
                vb4[0], pA, o_[qt][4], 0, 0, 0);
            o_[qt][4] = __builtin_amdgcn_mfma_f32_16x16x32_bf16(
                vb4[1], pB, o_[qt][4], 0, 0, 0);
            __builtin_amdgcn_s_setprio(0);
        }
    }

#pragma unroll
    for (int qt = 0; qt < 4; ++qt) {
        float lsum = __shfl(o_[qt][4][0], lo, 64);
        float inv = fast_rcp(lsum);
        const size_t rb = base + (size_t)(q0 + wq * 64 + qt * 16 + lo) * 1024;
#pragma unroll
        for (int db = 0; db < 4; ++db) {
            *(ushort4*)(O + rb + 16 * db + 4 * hi) = make_ushort4(
                f2bf(o_[qt][db][0] * inv), f2bf(o_[qt][db][1] * inv),
                f2bf(o_[qt][db][2] * inv), f2bf(o_[qt][db][3] * inv));
        }
    }
}

// ---------------------------------------------------------------------------
// Score GEMM + tanh clip + 1x1 conv + 2-way softmax.  64x128 tile,
// grid(1024) XCD-swizzled.  Fast transcendentals + v_rcp.
// ---------------------------------------------------------------------------
__global__ __launch_bounds__(256) void score_bf16(
    const unsigned short* __restrict__ MH, const unsigned short* __restrict__ EJ,
    const float* __restrict__ xt, const float* __restrict__ convw,
    const float* __restrict__ convb, float* __restrict__ out)
{
    __shared__ unsigned short As0[64 * 32], As1[64 * 32];
    __shared__ unsigned short Bs0[128 * 32], Bs1[128 * 32];
    const int orig = blockIdx.x;
    const int sw = (orig & 7) * 128 + (orig >> 3);
    const int bz = sw >> 7;
    const int m0 = ((sw >> 3) & 15) * 64, n0 = (sw & 7) * 128;
    const unsigned short* A = MH + (size_t)bz * N_ * E_;
    const unsigned short* Bm = EJ + (size_t)bz * N_ * E_;

    f32x4 acc[2][4];
    gemm_loop64(A, Bm, m0, n0, 1024, As0, As1, Bs0, Bs1, acc);

    const int lane = threadIdx.x & 63, wave = threadIdx.x >> 6;
    const int wm = wave >> 1, wn = wave & 1;
    const int fr = lane & 15, fq4 = (lane >> 4) * 4;
    const float w00 = convw[0], w01 = convw[1], w10 = convw[2], w11 = convw[3];
    const float cb0 = convb[0], cb1 = convb[1];
    const float L2E = 1.4426950408889634f;
    const float kT = -2.f * L2E * 0.03125f;
#pragma unroll
    for (int i = 0; i < 2; ++i) {
#pragma unroll
        for (int rr = 0; rr < 4; ++rr) {
            int row = m0 + wm * 32 + i * 16 + fq4 + rr;
            const float* xrow = xt + ((size_t)bz * N_ + row) * N_;
            float2* orow = (float2*)(out + (((size_t)bz * N_ + row) * N_) * 2);
#pragma unroll
            for (int j = 0; j < 4; ++j) {
                int col = n0 + wn * 64 + j * 16 + fr;
                float e = exp2f(acc[i][j][rr] * kT);
                float sc_ = fmaf(20.f, fast_rcp(1.f + e), -10.f);  // 10*tanh
                float x = xrow[col];
                float c0 = fmaf(w00, sc_, fmaf(w01, x, cb0));
                float c1 = fmaf(w10, sc_, fmaf(w11, x, cb1));
                float e1 = exp2f((c1 - c0) * L2E);
                float o0 = fast_rcp(1.f + e1);
                orow[col] = make_float2(o0, 1.f - o0);
            }
        }
    }
}

// ---------------------------------------------------------------------------
extern "C" void kernel_launch(void* const* d_in, const int* in_sizes, int n_in,
                              void* d_out, int out_size, void* d_ws, size_t ws_size,
                              hipStream_t stream)
{
    (void)in_sizes; (void)n_in; (void)out_size; (void)ws_size;
    const float* t     = (const float*)d_in[0];
    const float* ej    = (const float*)d_in[1];
    const float* xt    = (const float*)d_in[2];
    const float* Wq    = (const float*)d_in[3];
    const float* Wk    = (const float*)d_in[4];
    const float* Wv    = (const float*)d_in[5];
    const float* Wc    = (const float*)d_in[6];
    const float* bc    = (const float*)d_in[7];
    const float* convw = (const float*)d_in[8];
    const float* convb = (const float*)d_in[9];
    const float* tW1   = (const float*)d_in[10];
    const float* tb1   = (const float*)d_in[11];
    const float* tW2   = (const float*)d_in[12];
    const float* tb2   = (const float*)d_in[13];
    float* out = (float*)d_out;

    const size_t SZ = (size_t)B_ * N_ * 1024;
    float* ws = (float*)d_ws;
    float* temb = ws;                    // 8192 f32
    float* h1T  = ws + 8192;             // 4096 f32
    unsigned short* ej_bf = (unsigned short*)(ws + 8192 + 4096);
    unsigned short* MH_bf = ej_bf + SZ;
    unsigned short* Wq_bf = MH_bf + SZ;
    unsigned short* Wk_bf = Wq_bf + (size_t)E_ * 1024;
    unsigned short* Wv_bf = Wk_bf + (size_t)E_ * 1024;
    unsigned short* Wc_bf = Wv_bf + (size_t)E_ * 1024;

    unsigned short* Qb = (unsigned short*)d_out;  // Q|K|V|O bf16 = 64MB exactly
    unsigned short* Kb = Qb + SZ;
    unsigned short* Vb = Kb + SZ;
    unsigned short* Ob = Vb + SZ;

    cvt_fused<<<dim3(12416), dim3(256), 0, stream>>>(
        ej, Wq, Wk, Wv, Wc, ej_bf, Wq_bf, Wk_bf, Wv_bf, Wc_bf,
        t, tW1, tb1, h1T);

    dim3 gblk(256);
    qkv_gemm<<<dim3(1792), gblk, 0, stream>>>(
        ej_bf, Wq_bf, Wk_bf, Wv_bf, Qb, Kb, Vb, h1T, tW2, tb2, temb);

    attn_mfma<<<dim3(512), gblk, 0, stream>>>(Qb, Kb, Vb, Ob);

    outproj_gemm<<<dim3(1024), gblk, 0, stream>>>(Ob, Wc_bf, MH_bf, bc, temb);

    score_bf16<<<dim3(1024), gblk, 0, stream>>>(
        MH_bf, ej_bf, xt, convw, convb, out);
}